// Round 1
// baseline (482.793 us; speedup 1.0000x reference)
//
#include <hip/hip_runtime.h>

// Sinkhorn-Knopp on B independent 8x8 fp32 matrices.
//
// Layout: 16 threads per matrix, each thread owns one float4 = half a row.
//   lane t (t = tid & 15): row = t>>1, columns (t&1)*4 .. (t&1)*4+3
//
// Global loads/stores are perfectly coalesced: thread tid accesses
// ((float4*)x)[tid], i.e. lane-contiguous 16 B — one wave instruction
// covers 1 KiB of contiguous memory (the 64-matrix block's data in order).
//
// Row sums:   partner lane (t^1) holds the other half of the row -> 1 shfl_xor.
// Col sums:   rows of a matrix live on lanes with the same (t&1) at xor
//             distances {2,4,8} -> 3 shfl_xor rounds per component.
// All shuffle masks < 32 -> ds_swizzle_b32, no LDS allocation, no barriers.
//
// Memory-bound target: 512 MiB total traffic / ~6.3 TB/s ≈ 85 us.

#define N 8

__global__ __launch_bounds__(256) void sinkhorn8_kernel(
    const float* __restrict__ x,
    float* __restrict__ out,
    const int* __restrict__ num_iters_p,
    int B)
{
    int tid = blockIdx.x * blockDim.x + threadIdx.x;
    int m = tid >> 4;  // matrix index
    if (m >= B) return;

    const int num_iters = *num_iters_p;

    // Coalesced vector load: contiguous 16 B per lane.
    float4 v = ((const float4*)x)[tid];

    v.x = __expf(v.x);
    v.y = __expf(v.y);
    v.z = __expf(v.z);
    v.w = __expf(v.w);

    for (int it = 0; it < num_iters; ++it) {
        // ---- Row normalize ----
        // Local half-row sum, then add partner half from lane^1.
        float rs = v.x + v.y + v.z + v.w;
        rs += __shfl_xor(rs, 1, 64);
        float rinv = __builtin_amdgcn_rcpf(rs);
        v.x *= rinv;
        v.y *= rinv;
        v.z *= rinv;
        v.w *= rinv;

        // ---- Col normalize ----
        // Reduce each component across the 8 rows (lanes at xor 2,4,8).
        float4 cs = v;
#pragma unroll
        for (int d = 2; d <= 8; d <<= 1) {
            cs.x += __shfl_xor(cs.x, d, 64);
            cs.y += __shfl_xor(cs.y, d, 64);
            cs.z += __shfl_xor(cs.z, d, 64);
            cs.w += __shfl_xor(cs.w, d, 64);
        }
        v.x *= __builtin_amdgcn_rcpf(cs.x);
        v.y *= __builtin_amdgcn_rcpf(cs.y);
        v.z *= __builtin_amdgcn_rcpf(cs.z);
        v.w *= __builtin_amdgcn_rcpf(cs.w);
    }

    // Coalesced vector store.
    ((float4*)out)[tid] = v;
}

extern "C" void kernel_launch(void* const* d_in, const int* in_sizes, int n_in,
                              void* d_out, int out_size, void* d_ws, size_t ws_size,
                              hipStream_t stream) {
    const float* x = (const float*)d_in[0];
    const int* num_iters = (const int*)d_in[1];
    float* out = (float*)d_out;

    int B = in_sizes[0] / (N * N);  // number of 8x8 matrices
    long long total_threads = (long long)B * 16;
    int block = 256;
    long long grid = (total_threads + block - 1) / block;

    sinkhorn8_kernel<<<(int)grid, block, 0, stream>>>(x, out, num_iters, B);
}

// Round 2
// 411.694 us; speedup vs baseline: 1.1727x; 1.1727x over previous
//
#include <hip/hip_runtime.h>

// Sinkhorn-Knopp on B independent 8x8 fp32 matrices.
//
// 16 threads per matrix, one float4 (half a row) per thread, with a lane-bit
// remap chosen so the cross-lane reductions run on the VALU via DPP instead
// of the DS pipe (ds_swizzle), which was the Round-1 bottleneck
// (65 DS instr/wave ≈ 94 cyc/matrix on the per-CU LDS pipe vs ~50 cyc/matrix
//  memory floor).
//
// Lane mapping within a 16-lane group (t = lane & 15):
//   row bits  = lane bits {0,1,3}   (row = (t&3) | ((t>>1)&4))
//   half-col  = lane bit 2          (h = (t>>2)&1, columns h*4 .. h*4+3)
//
//   Column reduction (across 8 rows)  = butterfly over lane xor {1,2,8}:
//       xor1 -> DPP quad_perm [1,0,3,2] (0xB1)
//       xor2 -> DPP quad_perm [2,3,0,1] (0x4E)
//       xor8 -> DPP row_ror:8 (0x128)   (rot-8 within 16 lanes == xor 8)
//     -> all VALU, zero DS instructions.
//   Row-partner exchange = lane xor 4 -> one ds_swizzle per iteration
//     (5 total per thread; ~1.25 DS instr/matrix, negligible).
//
// The remap only permutes which float4 a lane loads *within* its 16-lane
// group; each wave load still covers one contiguous 1 KiB segment.
//
// Memory-bound target: 512 MiB traffic / ~6.3 TB/s ≈ 85 us.

#define N 8

template <int CTRL>
__device__ __forceinline__ float dpp_xor(float x) {
    int r = __builtin_amdgcn_update_dpp(0, __float_as_int(x), CTRL, 0xF, 0xF, true);
    return __int_as_float(r);
}

__global__ __launch_bounds__(256) void sinkhorn8_kernel(
    const float* __restrict__ x,
    float* __restrict__ out,
    const int* __restrict__ num_iters_p,
    int B)
{
    int tid = blockIdx.x * blockDim.x + threadIdx.x;
    int m = tid >> 4;  // matrix index
    if (m >= B) return;

    const int num_iters = *num_iters_p;

    // Lane-bit remap: row on bits {0,1,3}, column-half on bit 2.
    int t = tid & 15;
    int row = (t & 3) | ((t >> 1) & 4);
    int h = (t >> 2) & 1;
    size_t idx = ((size_t)m << 4) + (size_t)(row * 2 + h);

    // Coalesced vector load: 16 lanes cover one contiguous 1 KiB segment.
    float4 v = ((const float4*)x)[idx];

    v.x = __expf(v.x);
    v.y = __expf(v.y);
    v.z = __expf(v.z);
    v.w = __expf(v.w);

    for (int it = 0; it < num_iters; ++it) {
        // ---- Row normalize ----
        // Partner (other half of the row) is at lane xor 4.
        float rs = v.x + v.y + v.z + v.w;
        rs += __shfl_xor(rs, 4, 64);
        float rinv = __builtin_amdgcn_rcpf(rs);
        v.x *= rinv;
        v.y *= rinv;
        v.z *= rinv;
        v.w *= rinv;

        // ---- Col normalize ----
        // Butterfly across the 8 rows = lane xor {1,2,8}, all via DPP (VALU).
        float4 cs = v;
        cs.x += dpp_xor<0xB1>(cs.x);
        cs.y += dpp_xor<0xB1>(cs.y);
        cs.z += dpp_xor<0xB1>(cs.z);
        cs.w += dpp_xor<0xB1>(cs.w);

        cs.x += dpp_xor<0x4E>(cs.x);
        cs.y += dpp_xor<0x4E>(cs.y);
        cs.z += dpp_xor<0x4E>(cs.z);
        cs.w += dpp_xor<0x4E>(cs.w);

        cs.x += dpp_xor<0x128>(cs.x);
        cs.y += dpp_xor<0x128>(cs.y);
        cs.z += dpp_xor<0x128>(cs.z);
        cs.w += dpp_xor<0x128>(cs.w);

        v.x *= __builtin_amdgcn_rcpf(cs.x);
        v.y *= __builtin_amdgcn_rcpf(cs.y);
        v.z *= __builtin_amdgcn_rcpf(cs.z);
        v.w *= __builtin_amdgcn_rcpf(cs.w);
    }

    // Coalesced vector store (same permuted-in-group index).
    ((float4*)out)[idx] = v;
}

extern "C" void kernel_launch(void* const* d_in, const int* in_sizes, int n_in,
                              void* d_out, int out_size, void* d_ws, size_t ws_size,
                              hipStream_t stream) {
    const float* x = (const float*)d_in[0];
    const int* num_iters = (const int*)d_in[1];
    float* out = (float*)d_out;

    int B = in_sizes[0] / (N * N);  // number of 8x8 matrices
    long long total_threads = (long long)B * 16;
    int block = 256;
    long long grid = (total_threads + block - 1) / block;

    sinkhorn8_kernel<<<(int)grid, block, 0, stream>>>(x, out, num_iters, B);
}